// Round 3
// baseline (579.219 us; speedup 1.0000x reference)
//
#include <hip/hip_runtime.h>
#include <math.h>

#define SIGMA_F 32.0f
#define BB 8
#define CC 31
#define HH 512
#define WW 512
#define PLANE (HH * WW)
#define STAGE_CAP 12288   // floats of LDS staging (48 KB)

// ---- compile-time Gaussian weights: W[i] = exp(-i^2 / 2048), i in [0,63) ----
constexpr double cexp_neg(double t) {   // e^{-t}, t in [0, ~2]
    double u = -t / 16.0;
    double s = 1.0, term = 1.0;
    for (int k = 1; k < 14; ++k) { term *= u / (double)k; s += term; }
    s = s * s; s = s * s; s = s * s; s = s * s;   // ^16
    return s;
}
constexpr float gwf(int i) { return (float)cexp_neg((double)(i * i) / 2048.0); }

__device__ constexpr float W[64] = {
    gwf(0),  gwf(1),  gwf(2),  gwf(3),  gwf(4),  gwf(5),  gwf(6),  gwf(7),
    gwf(8),  gwf(9),  gwf(10), gwf(11), gwf(12), gwf(13), gwf(14), gwf(15),
    gwf(16), gwf(17), gwf(18), gwf(19), gwf(20), gwf(21), gwf(22), gwf(23),
    gwf(24), gwf(25), gwf(26), gwf(27), gwf(28), gwf(29), gwf(30), gwf(31),
    gwf(32), gwf(33), gwf(34), gwf(35), gwf(36), gwf(37), gwf(38), gwf(39),
    gwf(40), gwf(41), gwf(42), gwf(43), gwf(44), gwf(45), gwf(46), gwf(47),
    gwf(48), gwf(49), gwf(50), gwf(51), gwf(52), gwf(53), gwf(54), gwf(55),
    gwf(56), gwf(57), gwf(58), gwf(59), gwf(60), gwf(61), gwf(62), 0.0f
};

// Fused separable blur + per-block max (unchanged from round 2; ~few us).
__global__ __launch_bounds__(256, 2) void blur_fused_kernel(const float* __restrict__ dxn,
                                                            const float* __restrict__ dyn,
                                                            float* __restrict__ blur,
                                                            float* __restrict__ partials) {
    __shared__ __align__(16) float vt[16 * 580];
    __shared__ float smax[4];
    int t = threadIdx.x;
    int blk = blockIdx.x;
    int plane = blk >> 5;
    int band = blk & 31;
    int y0 = band << 4;
    const float* src = (plane < BB) ? dxn + (size_t)plane * PLANE
                                    : dyn + (size_t)(plane - BB) * PLANE;

    for (int c = t; c < 574; c += 256) {
        int L = c - 31;
        int scol = (L < 0) ? -L : ((L > HH - 1) ? 2 * HH - 2 - L : L);
        float acc[16];
        #pragma unroll
        for (int j = 0; j < 16; ++j) acc[j] = 0.0f;
        #pragma unroll
        for (int ro = 0; ro < 78; ++ro) {
            int rr = y0 - 31 + ro;
            int r = (rr < 0) ? -rr : ((rr > HH - 1) ? 2 * HH - 2 - rr : rr);
            float v = src[r * WW + scol];
            #pragma unroll
            for (int j = 0; j < 16; ++j) {
                int wi = ro - j;
                if (wi >= 0 && wi < 63) acc[j] += W[wi] * v;
            }
        }
        #pragma unroll
        for (int j = 0; j < 16; ++j) vt[j * 580 + c] = acc[j];
    }
    __syncthreads();

    float m = -INFINITY;
    int row = t & 15;
    int chunk0 = t >> 4;
    float* dstrow = blur + (size_t)plane * PLANE + (size_t)(y0 + row) * WW;
    const float* vrow = vt + row * 580;
    #pragma unroll
    for (int pass = 0; pass < 2; ++pass) {
        int x0 = (chunk0 + (pass << 4)) << 4;
        float acc[16];
        #pragma unroll
        for (int j = 0; j < 16; ++j) acc[j] = 0.0f;
        const float4* v4 = (const float4*)(vrow + x0);
        #pragma unroll
        for (int mi = 0; mi < 20; ++mi) {
            float4 vv = v4[mi];
            #pragma unroll
            for (int e = 0; e < 4; ++e) {
                float xv = (e == 0) ? vv.x : (e == 1) ? vv.y : (e == 2) ? vv.z : vv.w;
                int k = (mi << 2) + e;
                #pragma unroll
                for (int j = 0; j < 16; ++j) {
                    int wi = k - j;
                    if (wi >= 0 && wi < 63) acc[j] += W[wi] * xv;
                }
            }
        }
        #pragma unroll
        for (int j = 0; j < 16; ++j) m = fmaxf(m, acc[j]);
        float4* dst4 = (float4*)(dstrow + x0);
        #pragma unroll
        for (int q = 0; q < 4; ++q)
            dst4[q] = make_float4(acc[4 * q], acc[4 * q + 1], acc[4 * q + 2], acc[4 * q + 3]);
    }

    for (int off = 32; off; off >>= 1) m = fmaxf(m, __shfl_down(m, off, 64));
    if ((t & 63) == 0) smax[t >> 6] = m;
    __syncthreads();
    if (t == 0)
        partials[blk] = fmaxf(fmaxf(smax[0], smax[1]), fmaxf(smax[2], smax[3]));
}

__global__ __launch_bounds__(256) void reduce_max_kernel(const float* __restrict__ partials,
                                                         float* __restrict__ maxv) {
    int f = blockIdx.x;
    int t = threadIdx.x;
    float m = partials[f * 256 + t];
    __shared__ float smax[4];
    for (int off = 32; off; off >>= 1) m = fmaxf(m, __shfl_down(m, off, 64));
    if ((t & 63) == 0) smax[t >> 6] = m;
    __syncthreads();
    if (t == 0)
        maxv[f] = fmaxf(fmaxf(smax[0], smax[1]), fmaxf(smax[2], smax[3]));
}

// Tiled warp kernel: per 32x32 output tile, compute dynamic input bbox,
// stage it in LDS per channel, sample 4 taps from LDS.
// wid = b*256 + tile; XCD k (bid%8) owns batch image k entirely.
__global__ __launch_bounds__(256) void warp_tiled_kernel(const float* __restrict__ xin,
                                                         const float* __restrict__ blur,
                                                         const float* __restrict__ maxv,
                                                         float* __restrict__ warped,
                                                         float2* __restrict__ gridout) {
    __shared__ __align__(16) float stage[STAGE_CAP];
    __shared__ float rminx[4], rmaxx[4], rminy[4], rmaxy[4];
    __shared__ int sbox[4];

    int bid = blockIdx.x;
    int wid = (bid & 7) * 256 + (bid >> 3);
    int b = wid >> 8;
    int tile = wid & 255;
    int ty0 = (tile >> 4) << 5;
    int tx0 = (tile & 15) << 5;
    int t = threadIdx.x;

    float sx = SIGMA_F / maxv[0];
    float sy = SIGMA_F / maxv[1];

    int   x0i[4], y0i[4], dx1[4], dy1[4], gidx[4];
    float w00[4], w01[4], w10[4], w11[4];
    float mnx = 1e30f, mxx = -1e30f, mny = 1e30f, mxy = -1e30f;

    #pragma unroll
    for (int k = 0; k < 4; ++k) {
        int flat = k * 256 + t;
        int row = flat >> 5, col = flat & 31;
        int gy = ty0 + row, gx = tx0 + col;
        float dxv = blur[(size_t)b * PLANE + gy * WW + gx] * sx;
        float dyv = blur[(size_t)(BB + b) * PLANE + gy * WW + gx] * sy;
        float gnx = 2.0f * ((float)gx + dxv) / 511.0f - 1.0f;
        float gny = 2.0f * ((float)gy + dyv) / 511.0f - 1.0f;
        gridout[((size_t)b * HH + gy) * WW + gx] = make_float2(gnx, gny);
        float ix = (gnx + 1.0f) * 0.5f * 511.0f;
        float iy = (gny + 1.0f) * 0.5f * 511.0f;
        ix = fminf(fmaxf(ix, 0.0f), 511.0f);
        iy = fminf(fmaxf(iy, 0.0f), 511.0f);
        float fx = floorf(ix), fy = floorf(iy);
        float wx = ix - fx, wy = iy - fy;
        int x0 = (int)fx, y0 = (int)fy;
        x0i[k] = x0;  y0i[k] = y0;
        dx1[k] = (x0 < WW - 1) ? 1 : 0;
        dy1[k] = (y0 < HH - 1) ? 1 : 0;
        w00[k] = (1.0f - wx) * (1.0f - wy);
        w01[k] = wx * (1.0f - wy);
        w10[k] = (1.0f - wx) * wy;
        w11[k] = wx * wy;
        gidx[k] = gy * WW + gx;
        mnx = fminf(mnx, ix); mxx = fmaxf(mxx, ix);
        mny = fminf(mny, iy); mxy = fmaxf(mxy, iy);
    }

    for (int off = 32; off; off >>= 1) {
        mnx = fminf(mnx, __shfl_xor(mnx, off, 64));
        mxx = fmaxf(mxx, __shfl_xor(mxx, off, 64));
        mny = fminf(mny, __shfl_xor(mny, off, 64));
        mxy = fmaxf(mxy, __shfl_xor(mxy, off, 64));
    }
    if ((t & 63) == 0) {
        int wv = t >> 6;
        rminx[wv] = mnx; rmaxx[wv] = mxx; rminy[wv] = mny; rmaxy[wv] = mxy;
    }
    __syncthreads();
    if (t == 0) {
        float a = fminf(fminf(rminx[0], rminx[1]), fminf(rminx[2], rminx[3]));
        float bmx = fmaxf(fmaxf(rmaxx[0], rmaxx[1]), fmaxf(rmaxx[2], rmaxx[3]));
        float c = fminf(fminf(rminy[0], rminy[1]), fminf(rminy[2], rminy[3]));
        float d = fmaxf(fmaxf(rmaxy[0], rmaxy[1]), fmaxf(rmaxy[2], rmaxy[3]));
        int X0 = (int)floorf(a);
        int X1 = min((int)floorf(bmx) + 1, WW - 1);
        int Y0 = (int)floorf(c);
        int Y1 = min((int)floorf(d) + 1, HH - 1);
        sbox[0] = X0; sbox[1] = Y0; sbox[2] = X1 - X0 + 1; sbox[3] = Y1 - Y0 + 1;
    }
    __syncthreads();
    int X0 = sbox[0], Y0 = sbox[1], Wd = sbox[2], Ht = sbox[3];

    const float* xb = xin + (size_t)b * CC * PLANE;
    float* wb = warped + (size_t)b * CC * PLANE;

    if (Ht * Wd <= STAGE_CAP) {
        int sb0[4], sb2[4];
        #pragma unroll
        for (int k = 0; k < 4; ++k) {
            sb0[k] = (y0i[k] - Y0) * Wd + (x0i[k] - X0);
            sb2[k] = sb0[k] + dy1[k] * Wd;
        }
        int lane = t & 63, wv = t >> 6;
        for (int c = 0; c < CC; ++c) {
            const float* src = xb + (size_t)c * PLANE + (size_t)Y0 * WW + X0;
            for (int r = wv; r < Ht; r += 4) {
                int rw = r * Wd, rg = r * WW;
                for (int q = lane; q < Wd; q += 64)
                    stage[rw + q] = src[rg + q];
            }
            __syncthreads();
            float* dstc = wb + (size_t)c * PLANE;
            #pragma unroll
            for (int k = 0; k < 4; ++k) {
                float v00 = stage[sb0[k]];
                float v01 = stage[sb0[k] + dx1[k]];
                float v10 = stage[sb2[k]];
                float v11 = stage[sb2[k] + dx1[k]];
                dstc[gidx[k]] = v00 * w00[k] + v01 * w01[k] + v10 * w10[k] + v11 * w11[k];
            }
            __syncthreads();
        }
    } else {
        // fallback: global gather (identical arithmetic)
        for (int c = 0; c < CC; ++c) {
            const float* src = xb + (size_t)c * PLANE;
            float* dstc = wb + (size_t)c * PLANE;
            #pragma unroll
            for (int k = 0; k < 4; ++k) {
                int o00 = y0i[k] * WW + x0i[k];
                int o10 = o00 + dy1[k] * WW;
                float v00 = src[o00], v01 = src[o00 + dx1[k]];
                float v10 = src[o10], v11 = src[o10 + dx1[k]];
                dstc[gidx[k]] = v00 * w00[k] + v01 * w01[k] + v10 * w10[k] + v11 * w11[k];
            }
        }
    }
}

extern "C" void kernel_launch(void* const* d_in, const int* in_sizes, int n_in,
                              void* d_out, int out_size, void* d_ws, size_t ws_size,
                              hipStream_t stream) {
    const float* x   = (const float*)d_in[0];
    const float* dxn = (const float*)d_in[1];
    const float* dyn = (const float*)d_in[2];

    float* ws = (float*)d_ws;
    float* blur     = ws;                       // 16*512*512 floats
    float* partials = ws + 4194304;             // 512 floats
    float* maxv     = ws + 4194304 + 512;       // 2 floats

    float* warped   = (float*)d_out;                               // 8*31*512*512
    float2* gridout = (float2*)((float*)d_out + (size_t)BB * CC * PLANE);

    blur_fused_kernel<<<16 * 32, 256, 0, stream>>>(dxn, dyn, blur, partials);
    reduce_max_kernel<<<2, 256, 0, stream>>>(partials, maxv);
    warp_tiled_kernel<<<BB * 256, 256, 0, stream>>>(x, blur, maxv, warped, gridout);
}